// Round 1
// baseline (570.458 us; speedup 1.0000x reference)
//
#include <hip/hip_runtime.h>
#include <math.h>

// Problem constants (fixed by the reference)
#define BB 2
#define NN 2048
#define MM 64
#define FF 128
#define HH 64   // H1 == H2 == 64

__device__ __forceinline__ float sigmoidf_(float x) {
    return 1.0f / (1.0f + expf(-x));
}

// ---------------------------------------------------------------------------
// Kernel 1: per-atom MLP forward + analytic input gradient.
// One wave (64 lanes) per atom, 4 atoms per 256-thread block.
// Weights staged transposed in LDS with stride 65 (bank-conflict-free:
// address (k*65+j) -> bank (k+j)%32, 2-way aliasing is free on gfx950).
// ---------------------------------------------------------------------------
__global__ __launch_bounds__(256) void mlp_kernel(
    const float* __restrict__ image,
    const float* __restrict__ W0,    // [HH, FF]
    const float* __restrict__ W1,    // [HH, HH]
    const float* __restrict__ Wout,  // [1, HH]
    float* __restrict__ g,           // [BB*NN, FF]
    float* __restrict__ Ei)          // [BB*NN]
{
    __shared__ float w0t[FF * 65];   // w0t[f*65 + j] = W0[j, f]
    __shared__ float w1t[HH * 65];   // w1t[k*65 + j] = W1[j, k]
    __shared__ float xs[4][FF];
    __shared__ float h0s[4][HH];
    __shared__ float ts[4][HH];

    const int tid  = threadIdx.x;
    const int wv   = tid >> 6;
    const int lane = tid & 63;

    // Stage weights transposed (coalesced global reads; LDS writes hit
    // banks (f+j)%32 -> conflict-free thanks to the 65 stride).
    for (int i = tid; i < HH * FF; i += 256) {
        int j = i >> 7, f = i & 127;
        w0t[f * 65 + j] = W0[i];
    }
    for (int i = tid; i < HH * HH; i += 256) {
        int j = i >> 6, k = i & 63;
        w1t[k * 65 + j] = W1[i];
    }
    {
        const int base = blockIdx.x * 4 * FF;
        for (int i = tid; i < 4 * FF; i += 256) {
            xs[i >> 7][i & 127] = image[base + i];
        }
    }
    __syncthreads();

    const int atom = blockIdx.x * 4 + wv;   // atom = b*NN + n

    // Layer 0: h0[lane] = sigmoid(sum_f W0[lane,f] * x[f])
    float z0 = 0.f;
    #pragma unroll 8
    for (int k = 0; k < FF; ++k) z0 += w0t[k * 65 + lane] * xs[wv][k];
    const float h0 = sigmoidf_(z0);
    h0s[wv][lane] = h0;
    __syncthreads();

    // Layer 1: h1[lane] = sigmoid(sum_k W1[lane,k] * h0[k])
    float z1 = 0.f;
    #pragma unroll 8
    for (int k = 0; k < HH; ++k) z1 += w1t[k * 65 + lane] * h0s[wv][k];
    const float h1 = sigmoidf_(z1);
    const float wo = Wout[lane];

    // Per-atom energy: Ei = sum_j h1[j] * Wout[j]  (wave reduce, width 64)
    float e = h1 * wo;
    #pragma unroll
    for (int o = 32; o > 0; o >>= 1) e += __shfl_xor(e, o);
    if (lane == 0) Ei[atom] = e;

    // Backward: t1 = sigmoid'(z1) * Wout
    const float t1 = h1 * (1.f - h1) * wo;
    ts[wv][lane] = t1;
    __syncthreads();

    // g1[lane] = sum_j W1[j, lane] * t1[j]
    float g1 = 0.f;
    #pragma unroll 8
    for (int j = 0; j < HH; ++j) g1 += w1t[lane * 65 + j] * ts[wv][j];
    const float t0 = h0 * (1.f - h0) * g1;
    __syncthreads();
    ts[wv][lane] = t0;
    __syncthreads();

    // g[f] = sum_j W0[j, f] * t0[j]   (f = lane and lane+64)
    float ga = 0.f, gb = 0.f;
    #pragma unroll 8
    for (int j = 0; j < HH; ++j) {
        const float t = ts[wv][j];
        ga += w0t[lane * 65 + j] * t;
        gb += w0t[(lane + 64) * 65 + j] * t;
    }
    g[(size_t)atom * FF + lane]      = ga;
    g[(size_t)atom * FF + 64 + lane] = gb;
}

// ---------------------------------------------------------------------------
// Kernel 2: Etot[b] = sum_n Ei[b, n]  (deterministic, no atomics)
// ---------------------------------------------------------------------------
__global__ __launch_bounds__(256) void etot_kernel(
    const float* __restrict__ Ei, float* __restrict__ out)
{
    const int b = blockIdx.x;
    const int tid = threadIdx.x;
    float s = 0.f;
    for (int i = tid; i < NN; i += 256) s += Ei[b * NN + i];
    #pragma unroll
    for (int o = 32; o > 0; o >>= 1) s += __shfl_xor(s, o);
    __shared__ float r[4];
    if ((tid & 63) == 0) r[tid >> 6] = s;
    __syncthreads();
    if (tid == 0) out[b] = r[0] + r[1] + r[2] + r[3];
}

// ---------------------------------------------------------------------------
// Kernel 3: force[b,n,c] = 1e10 * sum_{m,f} g[b, nei[b,n,m]-1, f] * dfeat[b,n,m,f,c]
// One 256-thread block per (b,n). Neighbor g-rows gathered into 32 KB LDS
// (masked rows zeroed), then dfeat streamed contiguously (12 B/lane).
// ---------------------------------------------------------------------------
__global__ __launch_bounds__(256) void force_kernel(
    const float* __restrict__ dfeat,     // [BB*NN, MM, FF, 3]
    const int*   __restrict__ neighbor,  // [BB*NN, MM], 1-based, 0 = pad
    const float* __restrict__ g,         // [BB*NN, FF]
    float* __restrict__ force)           // [BB*NN, 3]
{
    __shared__ __align__(16) float gs[MM * FF];  // 32 KB
    __shared__ int nb[MM];
    __shared__ float red[4][3];

    const int tid = threadIdx.x;
    const int bn  = blockIdx.x;          // b*NN + n
    const int b   = bn >> 11;            // / NN

    if (tid < MM) nb[tid] = neighbor[bn * MM + tid];
    __syncthreads();

    // Gather neighbor gradient rows into LDS (float4, masked rows -> 0).
    const float* gbase = g + (size_t)b * NN * FF;
    for (int i = tid; i < MM * (FF / 4); i += 256) {
        const int m   = i >> 5;
        const int f4  = i & 31;
        const int nei = nb[m];
        float4 v = make_float4(0.f, 0.f, 0.f, 0.f);
        if (nei > 0) {
            v = ((const float4*)(gbase + (size_t)(nei - 1) * FF))[f4];
        }
        ((float4*)gs)[i] = v;
    }
    __syncthreads();

    // Stream dfeat: thread handles (m,f) pairs; 12 contiguous bytes each.
    const float* df = dfeat + (size_t)bn * (MM * FF * 3);
    float ax = 0.f, ay = 0.f, az = 0.f;
    #pragma unroll 4
    for (int i = tid; i < MM * FF; i += 256) {
        const float gv = gs[i];
        const float* p = df + i * 3;
        ax += gv * p[0];
        ay += gv * p[1];
        az += gv * p[2];
    }

    // Wave reduce (width 64), then cross-wave via LDS.
    #pragma unroll
    for (int o = 32; o > 0; o >>= 1) {
        ax += __shfl_xor(ax, o);
        ay += __shfl_xor(ay, o);
        az += __shfl_xor(az, o);
    }
    const int wv = tid >> 6;
    if ((tid & 63) == 0) { red[wv][0] = ax; red[wv][1] = ay; red[wv][2] = az; }
    __syncthreads();
    if (tid < 3) {
        const float s = red[0][tid] + red[1][tid] + red[2][tid] + red[3][tid];
        force[bn * 3 + tid] = s * 1e10f;
    }
}

// ---------------------------------------------------------------------------
extern "C" void kernel_launch(void* const* d_in, const int* in_sizes, int n_in,
                              void* d_out, int out_size, void* d_ws, size_t ws_size,
                              hipStream_t stream) {
    const float* image    = (const float*)d_in[0];
    const float* dfeat    = (const float*)d_in[1];
    const int*   neighbor = (const int*)d_in[2];
    // d_in[3] = Egroup_weight, d_in[4] = divider: unused by the reference.
    const float* W0   = (const float*)d_in[5];
    const float* W1   = (const float*)d_in[6];
    const float* Wout = (const float*)d_in[7];

    float* out = (float*)d_out;                  // [0:2]=Etot, [2:]=force
    float* g   = (float*)d_ws;                   // BB*NN*FF floats (2 MB)
    float* Ei  = g + (size_t)BB * NN * FF;       // BB*NN floats

    mlp_kernel<<<BB * NN / 4, 256, 0, stream>>>(image, W0, W1, Wout, g, Ei);
    etot_kernel<<<BB, 256, 0, stream>>>(Ei, out);
    force_kernel<<<BB * NN, 256, 0, stream>>>(dfeat, neighbor, g, out + BB);
}